// Round 1
// baseline (137.920 us; speedup 1.0000x reference)
//
#include <hip/hip_runtime.h>

// CenterLoss: loss = ( sum_i |x_i - c_{label_i}|^2  +  B*(C-1)*1e-12 ) / B
// B=16384, C=1000, D=512.
//
// v2 changes vs previous (79.9 us) kernel:
//  * Per-lane accumulation across rows: the per-row clamp(d^2,1e-12,1e12) is
//    dropped. Justification: d^2 = sum_512 (x-c)^2, mean ~1024, sigma ~64 for
//    the fixed random-normal inputs; even the degenerate case d^2 == 0 changes
//    the loss by only 1e-12/B ~ 6e-17 (absolute bound 1e-12 on the raw sum),
//    orders of magnitude below fp32 ulp of the ~1024 output. This removes the
//    6-deep ds_bpermute shuffle chain from the per-row critical path (it ran
//    once per row = 16384 times; now once per wave = 8192 times, off the load
//    path).
//  * 2 rows per wave, all 16 float4 loads (8 x + 8 centers) issued as one
//    independent batch -> 2x memory-level parallelism per wave.
//  * Single fused kernel: block partials + last-block-done finalize using
//    agent-scope atomics (safe across non-coherent per-XCD L2s). Kills the
//    second launch node; counter is zeroed by a 4-byte memset node.

#define B_ROWS    16384
#define C_CLASSES 1000
#define D_DIM     512
#define GRID      2048          // 2048 blocks * 4 waves * 2 rows = 16384 rows

__global__ __launch_bounds__(256) void center_loss_fused(
    const float* __restrict__ x,
    const int*   __restrict__ labels,
    const float* __restrict__ centers,
    float*       __restrict__ out,
    float*       __restrict__ partials,
    unsigned int* __restrict__ counter)
{
    const int tid  = threadIdx.x;
    const int wave = tid >> 6;
    const int lane = tid & 63;
    const int row0 = (blockIdx.x * 4 + wave) * 2;   // 2 consecutive rows/wave

    // label loads first (they head the dependent gather chain)
    const int lab0 = labels[row0];
    const int lab1 = labels[row0 + 1];

    const float4* __restrict__ xr0 = (const float4*)(x + (size_t)row0 * D_DIM);
    const float4* __restrict__ xr1 = (const float4*)(x + (size_t)(row0 + 1) * D_DIM);
    const float4* __restrict__ cr0 = (const float4*)(centers + (size_t)lab0 * D_DIM);
    const float4* __restrict__ cr1 = (const float4*)(centers + (size_t)lab1 * D_DIM);

    // 512 floats = 128 float4 per row; 64 lanes x 2 coalesced float4 per row.
    // All 16 loads are mutually independent -> deep MLP.
    float4 xa0 = xr0[lane];
    float4 xb0 = xr0[lane + 64];
    float4 xa1 = xr1[lane];
    float4 xb1 = xr1[lane + 64];
    float4 ca0 = cr0[lane];
    float4 cb0 = cr0[lane + 64];
    float4 ca1 = cr1[lane];
    float4 cb1 = cr1[lane + 64];

    float acc;
    {
        float d0 = xa0.x - ca0.x, d1 = xa0.y - ca0.y;
        float d2 = xa0.z - ca0.z, d3 = xa0.w - ca0.w;
        float e0 = xb0.x - cb0.x, e1 = xb0.y - cb0.y;
        float e2 = xb0.z - cb0.z, e3 = xb0.w - cb0.w;
        acc = d0*d0 + d1*d1 + d2*d2 + d3*d3
            + e0*e0 + e1*e1 + e2*e2 + e3*e3;
    }
    {
        float d0 = xa1.x - ca1.x, d1 = xa1.y - ca1.y;
        float d2 = xa1.z - ca1.z, d3 = xa1.w - ca1.w;
        float e0 = xb1.x - cb1.x, e1 = xb1.y - cb1.y;
        float e2 = xb1.z - cb1.z, e3 = xb1.w - cb1.w;
        acc += d0*d0 + d1*d1 + d2*d2 + d3*d3
             + e0*e0 + e1*e1 + e2*e2 + e3*e3;
    }

    // one wave-64 reduction per wave (amortized over 2 rows, off load path)
    #pragma unroll
    for (int off = 32; off > 0; off >>= 1)
        acc += __shfl_down(acc, off, 64);

    __shared__ float wsum[4];
    if (lane == 0) wsum[wave] = acc;
    __syncthreads();

    __shared__ bool isLast;
    if (tid == 0) {
        float blockSum = wsum[0] + wsum[1] + wsum[2] + wsum[3];
        // deterministic per-block partial; agent scope so the last block
        // (possibly on another XCD with a non-coherent L2) sees it.
        __hip_atomic_store(&partials[blockIdx.x], blockSum,
                           __ATOMIC_RELAXED, __HIP_MEMORY_SCOPE_AGENT);
        unsigned prev = __hip_atomic_fetch_add(counter, 1u,
                           __ATOMIC_ACQ_REL, __HIP_MEMORY_SCOPE_AGENT);
        isLast = (prev == GRID - 1);
    }
    __syncthreads();

    if (isLast) {   // block-uniform: whole last block participates
        float v = 0.0f;
        #pragma unroll
        for (int i = 0; i < GRID / 256; ++i)
            v += __hip_atomic_load(&partials[tid + i * 256],
                                   __ATOMIC_RELAXED, __HIP_MEMORY_SCOPE_AGENT);
        #pragma unroll
        for (int off = 32; off > 0; off >>= 1)
            v += __shfl_down(v, off, 64);
        if (lane == 0) wsum[wave] = v;
        __syncthreads();
        if (tid == 0) {
            float tot = wsum[0] + wsum[1] + wsum[2] + wsum[3];
            // masked-out zeros clamp up to 1e-12 in the reference: B*(C-1) of them
            tot += (float)B_ROWS * (float)(C_CLASSES - 1) * 1e-12f;
            out[0] = tot / (float)B_ROWS;
        }
    }
}

extern "C" void kernel_launch(void* const* d_in, const int* in_sizes, int n_in,
                              void* d_out, int out_size, void* d_ws, size_t ws_size,
                              hipStream_t stream) {
    const float* x       = (const float*)d_in[0];
    const int*   labels  = (const int*)d_in[1];
    const float* centers = (const float*)d_in[2];
    float*       out     = (float*)d_out;

    unsigned int* counter  = (unsigned int*)d_ws;                 // 4 B
    float*        partials = (float*)((char*)d_ws + 256);         // GRID floats

    // workspace is poisoned by the harness each iteration -> re-zero counter.
    // (memset node is graph-capturable; only hipMalloc/Free/Memcpy/DeviceSync
    // are banned.)
    hipMemsetAsync(d_ws, 0, 4, stream);

    center_loss_fused<<<GRID, 256, 0, stream>>>(x, labels, centers, out,
                                                partials, counter);
}

// Round 2
// 101.782 us; speedup vs baseline: 1.3551x; 1.3551x over previous
//
#include <hip/hip_runtime.h>

// CenterLoss: loss = ( sum_i |x_i - c_{label_i}|^2  +  B*(C-1)*1e-12 ) / B
// B=16384, C=1000, D=512.
//
// v3 changes vs v2 (which regressed to 84-96 us kernel time):
//  * ROOT CAUSE of v2 regression: per-block ACQ_REL agent-scope fetch_add.
//    On gfx950 the 8 per-XCD L2s are non-coherent; agent-scope release/acquire
//    forces L2 writeback/invalidate PER BLOCK -> 2048 serialized cache
//    maintenance ops ~= the entire 84 us (VALUBusy 1.3%, hbm 290 GB/s: pure
//    stall, nothing busy).
//  * Fix: one hardware float atomic per block (global_atomic_add_f32 via
//    unsafeAtomicAdd). Plain device-scope RMW atomics are coherent across
//    XCDs (learn_hip m20) with NO cache maintenance. 2048 adds pipeline
//    through the L2 RMW units in << 1 us.
//  * Each block adds blockSum/B; block 0 also adds (C-1)*1e-12 (the reference's
//    masked-zero clamp contribution, ~1e-9 -- numerically invisible vs ~1022
//    but kept for fidelity). out[0] zeroed by a 4-byte memset graph node.
//  * Workspace completely unused: no counter, no partials, no finalize block.
//  * Per-row clamp(d^2,1e-12,1e12) remains dropped: d^2 ~ N(1024, 64); even
//    d^2==0 changes the raw sum by 1e-12 -> ~6e-17 on the loss. Unobservable
//    in fp32 (ulp of 1022 is ~6e-5).

#define B_ROWS    16384
#define C_CLASSES 1000
#define D_DIM     512
#define GRID      2048          // 2048 blocks * 4 waves * 2 rows = 16384 rows

__global__ __launch_bounds__(256) void center_loss_v3(
    const float* __restrict__ x,
    const int*   __restrict__ labels,
    const float* __restrict__ centers,
    float*       __restrict__ out)
{
    const int tid  = threadIdx.x;
    const int wave = tid >> 6;
    const int lane = tid & 63;
    const int row0 = (blockIdx.x * 4 + wave) * 2;   // 2 consecutive rows/wave

    // labels head the dependent gather chain -- issue first
    const int lab0 = labels[row0];
    const int lab1 = labels[row0 + 1];

    const float4* __restrict__ xr0 = (const float4*)(x + (size_t)row0 * D_DIM);
    const float4* __restrict__ xr1 = (const float4*)(x + (size_t)(row0 + 1) * D_DIM);
    const float4* __restrict__ cr0 = (const float4*)(centers + (size_t)lab0 * D_DIM);
    const float4* __restrict__ cr1 = (const float4*)(centers + (size_t)lab1 * D_DIM);

    // 512 floats = 128 float4 per row; 64 lanes x 2 coalesced float4 per row.
    // All 16 loads mutually independent -> deep memory-level parallelism.
    float4 xa0 = xr0[lane];
    float4 xb0 = xr0[lane + 64];
    float4 xa1 = xr1[lane];
    float4 xb1 = xr1[lane + 64];
    float4 ca0 = cr0[lane];
    float4 cb0 = cr0[lane + 64];
    float4 ca1 = cr1[lane];
    float4 cb1 = cr1[lane + 64];

    float acc;
    {
        float d0 = xa0.x - ca0.x, d1 = xa0.y - ca0.y;
        float d2 = xa0.z - ca0.z, d3 = xa0.w - ca0.w;
        float e0 = xb0.x - cb0.x, e1 = xb0.y - cb0.y;
        float e2 = xb0.z - cb0.z, e3 = xb0.w - cb0.w;
        acc = d0*d0 + d1*d1 + d2*d2 + d3*d3
            + e0*e0 + e1*e1 + e2*e2 + e3*e3;
    }
    {
        float d0 = xa1.x - ca1.x, d1 = xa1.y - ca1.y;
        float d2 = xa1.z - ca1.z, d3 = xa1.w - ca1.w;
        float e0 = xb1.x - cb1.x, e1 = xb1.y - cb1.y;
        float e2 = xb1.z - cb1.z, e3 = xb1.w - cb1.w;
        acc += d0*d0 + d1*d1 + d2*d2 + d3*d3
             + e0*e0 + e1*e1 + e2*e2 + e3*e3;
    }

    // wave-64 reduction (once per wave, off the load path)
    #pragma unroll
    for (int off = 32; off > 0; off >>= 1)
        acc += __shfl_down(acc, off, 64);

    __shared__ float wsum[4];
    if (lane == 0) wsum[wave] = acc;
    __syncthreads();

    if (tid == 0) {
        float v = (wsum[0] + wsum[1] + wsum[2] + wsum[3]) * (1.0f / (float)B_ROWS);
        if (blockIdx.x == 0)
            v += (float)(C_CLASSES - 1) * 1e-12f;   // masked-zero clamp term
        // single HW fp32 atomic per block; device-scope, XCD-coherent,
        // no cache-maintenance traffic.
        unsafeAtomicAdd(out, v);
    }
}

extern "C" void kernel_launch(void* const* d_in, const int* in_sizes, int n_in,
                              void* d_out, int out_size, void* d_ws, size_t ws_size,
                              hipStream_t stream) {
    const float* x       = (const float*)d_in[0];
    const int*   labels  = (const int*)d_in[1];
    const float* centers = (const float*)d_in[2];
    float*       out     = (float*)d_out;

    // out[0] is the accumulator -- zero it each iteration (graph-capturable).
    hipMemsetAsync(out, 0, 4, stream);

    center_loss_v3<<<GRID, 256, 0, stream>>>(x, labels, centers, out);
}

// Round 3
// 79.206 us; speedup vs baseline: 1.7413x; 1.2850x over previous
//
#include <hip/hip_runtime.h>

// CenterLoss: loss = ( sum_i |x_i - c_{label_i}|^2  +  B*(C-1)*1e-12 ) / B
// B=16384, C=1000, D=512.
//
// v4: revert to the round-0 two-dispatch structure (it was never the
// bottleneck) while keeping v3's per-wave improvements.
//  * ROOT CAUSE of v2/v3 slowness: 2048 same-address RMW atomics on out[0].
//    All blocks retire within a few us -> arrival ~200/us at ONE cache line
//    at the device coherence point; same-address service ~25ns each ->
//    ~50us queueing, and the dispatch only ends when the last atomic lands.
//    (v2 = 50us serialization + 34us ACQ_REL L2 writeback/invalidate; v3 =
//    50us serialization. Both match measurement.)
//  * Fix: per-block partials via plain stores to DISTINCT addresses (zero
//    contention; end-of-dispatch implicit release makes them visible to the
//    next kernel -- proven correct in round 0), then a one-block finalize
//    kernel (~3us, measured in round 0).
//  * Kept from v3: per-lane accumulation across 2 rows/wave (per-row
//    clamp(d^2,1e-12,1e12) dropped -- d^2 ~ N(1024,64); even d^2==0 shifts
//    the loss by 1e-12/B ~ 6e-17, invisible at fp32 ulp ~6e-5), all 16
//    float4 loads issued as one independent batch, single shuffle chain per
//    wave off the load path.
//  * 2048 blocks x 256 thr, VGPR=24 -> 8 blocks/CU: the entire grid is
//    co-resident, so every load is in flight within ~0.5us -> HBM/L3
//    bandwidth-limited, not latency-limited. x (33.5MB) stays L3-resident
//    across bench iterations (round-2 FETCH_SIZE 24MB < 36MB logical).

#define B_ROWS    16384
#define C_CLASSES 1000
#define D_DIM     512
#define S1_BLOCKS 2048          // 2048 blocks * 4 waves * 2 rows = 16384 rows

__global__ __launch_bounds__(256) void center_loss_stage1(
    const float* __restrict__ x,
    const int*   __restrict__ labels,
    const float* __restrict__ centers,
    float*       __restrict__ partials)
{
    const int tid  = threadIdx.x;
    const int wave = tid >> 6;
    const int lane = tid & 63;
    const int row0 = (blockIdx.x * 4 + wave) * 2;   // 2 consecutive rows/wave

    // labels head the dependent gather chain -- issue first
    const int lab0 = labels[row0];
    const int lab1 = labels[row0 + 1];

    const float4* __restrict__ xr0 = (const float4*)(x + (size_t)row0 * D_DIM);
    const float4* __restrict__ xr1 = (const float4*)(x + (size_t)(row0 + 1) * D_DIM);
    const float4* __restrict__ cr0 = (const float4*)(centers + (size_t)lab0 * D_DIM);
    const float4* __restrict__ cr1 = (const float4*)(centers + (size_t)lab1 * D_DIM);

    // 512 floats = 128 float4 per row; 64 lanes x 2 coalesced float4 per row.
    // All 16 loads mutually independent -> deep memory-level parallelism.
    float4 xa0 = xr0[lane];
    float4 xb0 = xr0[lane + 64];
    float4 xa1 = xr1[lane];
    float4 xb1 = xr1[lane + 64];
    float4 ca0 = cr0[lane];
    float4 cb0 = cr0[lane + 64];
    float4 ca1 = cr1[lane];
    float4 cb1 = cr1[lane + 64];

    float acc;
    {
        float d0 = xa0.x - ca0.x, d1 = xa0.y - ca0.y;
        float d2 = xa0.z - ca0.z, d3 = xa0.w - ca0.w;
        float e0 = xb0.x - cb0.x, e1 = xb0.y - cb0.y;
        float e2 = xb0.z - cb0.z, e3 = xb0.w - cb0.w;
        acc = d0*d0 + d1*d1 + d2*d2 + d3*d3
            + e0*e0 + e1*e1 + e2*e2 + e3*e3;
    }
    {
        float d0 = xa1.x - ca1.x, d1 = xa1.y - ca1.y;
        float d2 = xa1.z - ca1.z, d3 = xa1.w - ca1.w;
        float e0 = xb1.x - cb1.x, e1 = xb1.y - cb1.y;
        float e2 = xb1.z - cb1.z, e3 = xb1.w - cb1.w;
        acc += d0*d0 + d1*d1 + d2*d2 + d3*d3
             + e0*e0 + e1*e1 + e2*e2 + e3*e3;
    }

    // wave-64 reduction (once per wave, off the load path)
    #pragma unroll
    for (int off = 32; off > 0; off >>= 1)
        acc += __shfl_down(acc, off, 64);

    __shared__ float wsum[4];
    if (lane == 0) wsum[wave] = acc;
    __syncthreads();

    if (tid == 0)
        partials[blockIdx.x] = wsum[0] + wsum[1] + wsum[2] + wsum[3];
}

__global__ __launch_bounds__(256) void center_loss_stage2(
    const float* __restrict__ partials,
    float*       __restrict__ out)
{
    const int tid  = threadIdx.x;
    const int wave = tid >> 6;
    const int lane = tid & 63;

    // 2048 partials = 512 float4; 256 threads x 2 float4
    const float4* __restrict__ p4 = (const float4*)partials;
    float4 a = p4[tid];
    float4 b = p4[tid + 256];
    float s = a.x + a.y + a.z + a.w + b.x + b.y + b.z + b.w;

    #pragma unroll
    for (int off = 32; off > 0; off >>= 1)
        s += __shfl_down(s, off, 64);

    __shared__ float lds[4];
    if (lane == 0) lds[wave] = s;
    __syncthreads();
    if (tid == 0) {
        float tot = lds[0] + lds[1] + lds[2] + lds[3];
        // masked-out zeros clamp up to 1e-12 in the reference: B*(C-1) of them
        tot += (float)B_ROWS * (float)(C_CLASSES - 1) * 1e-12f;
        out[0] = tot / (float)B_ROWS;
    }
}

extern "C" void kernel_launch(void* const* d_in, const int* in_sizes, int n_in,
                              void* d_out, int out_size, void* d_ws, size_t ws_size,
                              hipStream_t stream) {
    const float* x       = (const float*)d_in[0];
    const int*   labels  = (const int*)d_in[1];
    const float* centers = (const float*)d_in[2];
    float*       out     = (float*)d_out;
    float*       partials = (float*)d_ws;   // S1_BLOCKS floats = 8 KB

    center_loss_stage1<<<S1_BLOCKS, 256, 0, stream>>>(x, labels, centers, partials);
    center_loss_stage2<<<1, 256, 0, stream>>>(partials, out);
}